// Round 3
// baseline (1289.444 us; speedup 1.0000x reference)
//
#include <hip/hip_runtime.h>
#include <hip/hip_fp16.h>

#define TT   2048
#define BB   64
#define II   16
#define HH   8
#define HIDN 64
#define GG   256   // 4*HIDN
#define T4   (TT / 4)

typedef _Float16 h2 __attribute__((ext_vector_type(2)));
typedef _Float16 h4 __attribute__((ext_vector_type(4)));
typedef _Float16 h8 __attribute__((ext_vector_type(8)));
typedef float    f4 __attribute__((ext_vector_type(4)));

__device__ __forceinline__ float fdot2(h2 a, h2 b, float c) {
    return __builtin_amdgcn_fdot2(a, b, c, false);
}
__device__ __forceinline__ float fast_sigmoid(float z) {
    return __builtin_amdgcn_rcpf(1.0f + __expf(-z));
}
__device__ __forceinline__ float fast_tanh(float z) {
    return fmaf(2.0f, __builtin_amdgcn_rcpf(1.0f + __expf(-2.0f * z)), -1.0f);
}

// Swizzled LDS byte offset for element (b, u) of a [16 b][64 u] f16 tile.
// 16B granules along u; granule index XOR b spreads a wave's ds_read_b128
// granule-starts across bank pairs.
__device__ __forceinline__ int lds_off(int b, int u) {
    return b * 128 + ((((u >> 3) ^ b) & 7) << 4) + (u & 7) * 2;
}
__device__ __forceinline__ h8 cvt8(const float* p) {
    float4 v0 = ((const float4*)p)[0];
    float4 v1 = ((const float4*)p)[1];
    return h8{(_Float16)v0.x, (_Float16)v0.y, (_Float16)v0.z, (_Float16)v0.w,
              (_Float16)v1.x, (_Float16)v1.y, (_Float16)v1.z, (_Float16)v1.w};
}

// LDS-visibility-only barrier: drain ds ops, do NOT drain vmcnt (keeps the
// x prefetch loads and the slab stores in flight across the barrier).
__device__ __forceinline__ void sync_lds() {
    asm volatile("s_waitcnt lgkmcnt(0)" ::: "memory");
    __builtin_amdgcn_s_barrier();
    asm volatile("" ::: "memory");
}

// ---------------- x -> f16 conversion (one-time, trivial) ----------------
__global__ void cvt_x_kernel(const float* __restrict__ x, _Float16* __restrict__ xh, int n4) {
    int i = blockIdx.x * blockDim.x + threadIdx.x;
    if (i < n4) {
        float4 v = ((const float4*)x)[i];
        ((h2*)xh)[2 * i]     = h2{ (_Float16)v.x, (_Float16)v.y };
        ((h2*)xh)[2 * i + 1] = h2{ (_Float16)v.z, (_Float16)v.w };
    }
}

// ---------------- main recurrent kernel: MFMA-batched, register-tiled M ----
// One 256-thread block (4 waves) per (head, 16-batch group); grid = 32.
// z = W.h is a (256x64)@(64x16) matmul/step; wave w owns M-rows [64w,64w+64)
// as 4 M-tiles sharing ONE vb0/vb1 LDS read pair (4x operand reuse vs R2's
// 16-wave layout: per-step LDS reads drop 32->8, barrier is 4-wave,
// x-prefetch 16->4 loads). Row permutation per 16-row tile: r' = 4*u_loc + g
// so C-lane (hi,bl) of tile (w,mt) = gates {i,f,g,o}=reg 0..3 of unit
// 16w+4mt+hi, batch bl -> zero post-MFMA shuffling (verified layout).
__global__ __launch_bounds__(256)
void lstm_mfma(const _Float16* __restrict__ xh,
               const float* __restrict__ Wih,
               const float* __restrict__ Whh,
               const float* __restrict__ bih,
               const float* __restrict__ bhh,
               _Float16* __restrict__ stage_f16)   // [t4][chain][unit][4] h4
{
    const int tid  = threadIdx.x;
    const int w    = tid >> 6;          // wave 0..3: owns units 16w..16w+15
    const int lane = tid & 63;
    const int hi   = lane >> 4;         // k-group / C row-group
    const int bl   = lane & 15;         // batch-in-group (C col)
    const int hd   = blockIdx.x >> 2;
    const int bg   = blockIdx.x & 3;

    // ---- A fragments + bias per M-tile ----
    h8 a0[4], a1[4], a2[4];
    f4 biasv[4];
#pragma unroll
    for (int mt = 0; mt < 4; ++mt) {
        // permuted row fr=bl of tile (w,mt): gate g=fr&3, unit 16w+4mt+(fr>>2)
        const int rA = hd * GG + (bl & 3) * HIDN + 16 * w + 4 * mt + (bl >> 2);
        const float* pw = Whh + (size_t)rA * HIDN;
        a0[mt] = cvt8(pw + hi * 8);          // k = units hi*8..+7
        a1[mt] = cvt8(pw + 32 + hi * 8);     // k = units 32+hi*8..+7
        a2[mt] = h8{};                       // x K-tile, zero for k>=16
        if (hi < 2) a2[mt] = cvt8(Wih + (size_t)rA * II + hi * 8);
        const int u = 16 * w + 4 * mt + hi;  // this lane's unit for tile mt
#pragma unroll
        for (int g = 0; g < 4; ++g) {
            int r = hd * GG + g * HIDN + u;
            biasv[mt][g] = bih[r] + bhh[r];
        }
    }

    // ---- LDS: h double-buffer only (4 KB) ----
    __shared__ __align__(16) char hA[2048];
    __shared__ __align__(16) char hB[2048];

    const int off_b0 = lds_off(bl, hi * 8);        // B frag, k-tile 0
    const int off_b1 = lds_off(bl, 32 + hi * 8);   // B frag, k-tile 1
    int off_hw[4];
#pragma unroll
    for (int mt = 0; mt < 4; ++mt) off_hw[mt] = lds_off(bl, 16 * w + 4 * mt + hi);

    // ---- per-lane x pointer + 4-deep register prefetch (no clamp: the
    // <=8KB overrun past xh lands in the slab region of the workspace) ----
    const _Float16* xlane = xh + (size_t)(bg * 16 + bl) * II + (hi & 1) * 8;
    auto ldx = [&](int t) -> h8 {
        return *(const h8*)(xlane + (size_t)t * (BB * II));
    };

    // prologue: h(-1)=0, prime x pipeline
#pragma unroll
    for (int mt = 0; mt < 4; ++mt) *(_Float16*)(hA + off_hw[mt]) = (_Float16)0.0f;
    h8 xp0 = ldx(0), xp1 = ldx(1), xp2 = ldx(2), xp3 = ldx(3);
    sync_lds();

    float cst[4] = {0.f, 0.f, 0.f, 0.f};
    // slab base: h4 index = chain*64 + unit, unit = 16w+4mt+hi -> +4 per mt
    h4* sbase = (h4*)stage_f16 + (size_t)(hd * 64 + bg * 16 + bl) * 64 + 16 * w + hi;

#define STEP(jj, CURH, NXTH, XP) do {                                           \
        f4 acc[4];                                                              \
        _Pragma("unroll")                                                       \
        for (int mt = 0; mt < 4; ++mt)                                          \
            acc[mt] = __builtin_amdgcn_mfma_f32_16x16x32_f16(a2[mt], XP,        \
                                                             biasv[mt], 0,0,0); \
        XP = ldx(t0 + jj + 4);          /* refill, consumed 4 steps later */    \
        h8 vb0 = *(const h8*)(CURH + off_b0);                                   \
        h8 vb1 = *(const h8*)(CURH + off_b1);                                   \
        _Pragma("unroll")                                                       \
        for (int mt = 0; mt < 4; ++mt)                                          \
            acc[mt] = __builtin_amdgcn_mfma_f32_16x16x32_f16(a0[mt], vb0,       \
                                                             acc[mt], 0, 0, 0); \
        _Pragma("unroll")                                                       \
        for (int mt = 0; mt < 4; ++mt)                                          \
            acc[mt] = __builtin_amdgcn_mfma_f32_16x16x32_f16(a1[mt], vb1,       \
                                                             acc[mt], 0, 0, 0); \
        _Pragma("unroll")                                                       \
        for (int mt = 0; mt < 4; ++mt) {                                        \
            float gi = fast_sigmoid(acc[mt][0]);                                \
            float gf = fast_sigmoid(acc[mt][1]);                                \
            float gg = fast_tanh(acc[mt][2]);                                   \
            float go = fast_sigmoid(acc[mt][3]);                                \
            cst[mt] = fmaf(gf, cst[mt], gi * gg);                               \
            float hv = go * fast_tanh(cst[mt]);                                 \
            _Float16 h16 = (_Float16)hv;                                        \
            *(_Float16*)(NXTH + off_hw[mt]) = h16;                              \
            hpk[mt].e[jj] = h16;                                                \
        }                                                                       \
        sync_lds();                                                             \
    } while (0)

    for (int t4 = 0; t4 < T4; ++t4) {
        const int t0 = 4 * t4;
        union { h4 v4; _Float16 e[4]; } hpk[4];
        STEP(0, hA, hB, xp0);
        STEP(1, hB, hA, xp1);
        STEP(2, hA, hB, xp2);
        STEP(3, hB, hA, xp3);
#pragma unroll
        for (int mt = 0; mt < 4; ++mt)
            sbase[4 * mt] = hpk[mt].v4;   // 8B fire-and-forget, never drained
        sbase += 512 * 64;
    }
#undef STEP
}

// ---------------- legacy one-wave-per-chain kernel (workspace fallback) ----------------
template <int STAGE, bool XF16>
__global__ __launch_bounds__(64, 1)
void lstm_wave(const float* __restrict__ x,
               const _Float16* __restrict__ xh,
               const float* __restrict__ Wih,
               const float* __restrict__ Whh,
               const float* __restrict__ bih,
               const float* __restrict__ bhh,
               const float* __restrict__ Wlin,
               const float* __restrict__ blin,
               float* __restrict__ out,
               float* __restrict__ lstm_out,
               _Float16* __restrict__ stage_f16)
{
    const int lane = threadIdx.x;
    const int c    = blockIdx.x;
    const int b    = c & (BB - 1);
    const int hd   = c >> 6;

    h2 whh[4][HIDN / 2];
    h2 wih[4][II / 2];
    float bias[4];
#pragma unroll
    for (int g = 0; g < 4; ++g) {
        const int r = hd * GG + g * HIDN + lane;
        const float4* p = (const float4*)(Whh + (size_t)r * HIDN);
#pragma unroll
        for (int q = 0; q < HIDN / 4; ++q) {
            float4 v = p[q];
            whh[g][2 * q]     = h2{ (_Float16)v.x, (_Float16)v.y };
            whh[g][2 * q + 1] = h2{ (_Float16)v.z, (_Float16)v.w };
        }
        const float4* pi = (const float4*)(Wih + (size_t)r * II);
#pragma unroll
        for (int q = 0; q < II / 4; ++q) {
            float4 v = pi[q];
            wih[g][2 * q]     = h2{ (_Float16)v.x, (_Float16)v.y };
            wih[g][2 * q + 1] = h2{ (_Float16)v.z, (_Float16)v.w };
        }
        bias[g] = bih[r] + bhh[r];
    }
    float wl = 0.0f, blv = 0.0f;
    if (STAGE == 2) { wl = Wlin[hd * HIDN + lane]; blv = blin[hd]; }

    __shared__ __align__(16) _Float16 hbuf[HIDN];
    hbuf[lane] = (_Float16)0.0f;

    float cst = 0.0f;

    const _Float16* xhp = xh + b * II;
    const float*    xfp = x + b * II;
    h2 xv[II / 2];
    auto load_x = [&](int t, h2* dst) {
        int tc = t < TT ? t : TT - 1;
        if (XF16) {
            const h8* p = (const h8*)(xhp + (size_t)tc * BB * II);
            union { h8 v; h2 p2[4]; } u0, u1;
            u0.v = p[0];
            u1.v = p[1];
#pragma unroll
            for (int i = 0; i < 4; ++i) { dst[i] = u0.p2[i]; dst[4 + i] = u1.p2[i]; }
        } else {
            const float4* p = (const float4*)(xfp + (size_t)tc * BB * II);
#pragma unroll
            for (int q = 0; q < 4; ++q) {
                float4 v = p[q];
                dst[2 * q]     = h2{ (_Float16)v.x, (_Float16)v.y };
                dst[2 * q + 1] = h2{ (_Float16)v.z, (_Float16)v.w };
            }
        }
    };
    load_x(0, xv);

    h4* sptr = (h4*)(stage_f16 + (size_t)c * 256 + lane * 4);

    for (int t4 = 0; t4 < T4; ++t4) {
        union { h4 v4; h2 p2[2]; } hp;
#pragma unroll
        for (int j = 0; j < 4; ++j) {
            const int t = t4 * 4 + j;
            h2 xn[II / 2];
            load_x(t + 1, xn);

            union { h8 v[8]; h2 p[32]; } hr;
#pragma unroll
            for (int q = 0; q < 8; ++q) hr.v[q] = ((const h8*)hbuf)[q];

            float z0 = bias[0], z1 = bias[1], z2 = bias[2], z3 = bias[3];
#pragma unroll
            for (int q = 0; q < HIDN / 2; ++q) {
                z0 = fdot2(whh[0][q], hr.p[q], z0);
                z1 = fdot2(whh[1][q], hr.p[q], z1);
                z2 = fdot2(whh[2][q], hr.p[q], z2);
                z3 = fdot2(whh[3][q], hr.p[q], z3);
            }
#pragma unroll
            for (int q = 0; q < II / 2; ++q) {
                z0 = fdot2(wih[0][q], xv[q], z0);
                z1 = fdot2(wih[1][q], xv[q], z1);
                z2 = fdot2(wih[2][q], xv[q], z2);
                z3 = fdot2(wih[3][q], xv[q], z3);
            }

            float gi = fast_sigmoid(z0);
            float gf = fast_sigmoid(z1);
            float gg = fast_tanh(z2);
            float go = fast_sigmoid(z3);

            cst = fmaf(gf, cst, gi * gg);
            float h = go * fast_tanh(cst);
            _Float16 h16 = (_Float16)h;

            hbuf[lane] = h16;
            hp.p2[j >> 1][j & 1] = h16;

            if (STAGE == 2) {
                atomicAdd(&lstm_out[((size_t)t * BB + b) * HIDN + lane], h);
                float p = h * wl;
                p += __shfl_down(p, 32, 64);
                p += __shfl_down(p, 16, 64);
                p += __shfl_down(p, 8, 64);
                p += __shfl_down(p, 4, 64);
                p += __shfl_down(p, 2, 64);
                p += __shfl_down(p, 1, 64);
                if (lane == 0) out[((size_t)t * BB + b) * HH + hd] = p + blv;
            }

#pragma unroll
            for (int q = 0; q < II / 2; ++q) xv[q] = xn[q];
        }
        if (STAGE == 1) {
            *sptr = hp.v4;
            sptr += 512 * 64;
        }
    }
}

// ---------------- pass 2a: lstm_out[t,b,k] = sum_hd h ----------------
__global__ __launch_bounds__(256)
void pass_lstm(const _Float16* __restrict__ stage, float* __restrict__ lstm_out)
{
    const int tid  = threadIdx.x;
    const int k    = tid & (HIDN - 1);
    const int q    = tid >> 6;
    const int b    = blockIdx.x & (BB - 1);
    const int tile = blockIdx.x >> 6;
    const h4* sp = (const h4*)stage;

#pragma unroll
    for (int g = 0; g < 4; ++g) {
        const int t4 = tile * 16 + q + 4 * g;
        float acc0 = 0.f, acc1 = 0.f, acc2 = 0.f, acc3 = 0.f;
#pragma unroll
        for (int hd = 0; hd < HH; ++hd) {
            h4 v = sp[((size_t)t4 * 512 + hd * 64 + b) * 64 + k];
            acc0 += (float)v.x; acc1 += (float)v.y;
            acc2 += (float)v.z; acc3 += (float)v.w;
        }
        const size_t t = (size_t)t4 * 4;
        lstm_out[((t + 0) * BB + b) * HIDN + k] = acc0;
        lstm_out[((t + 1) * BB + b) * HIDN + k] = acc1;
        lstm_out[((t + 2) * BB + b) * HIDN + k] = acc2;
        lstm_out[((t + 3) * BB + b) * HIDN + k] = acc3;
    }
}

// ---------------- pass 2b: out[t,b,hd] = dot(h, W_lin)+b_lin ----------------
__global__ __launch_bounds__(512)
void pass_out(const _Float16* __restrict__ stage,
              const float* __restrict__ Wlin,
              const float* __restrict__ blin,
              float* __restrict__ out)
{
    __shared__ float wls[GG * 2];
    const int tid = threadIdx.x;
    wls[tid] = Wlin[tid];
    __syncthreads();

    const int b  = tid >> 3;
    const int hd = tid & 7;
    const int c  = hd * 64 + b;
    const int t4 = blockIdx.x;
    const float bl = blin[hd];

    const h4* sp = (const h4*)stage + ((size_t)t4 * 512 + c) * 64;
    float a0 = 0.f, a1 = 0.f, a2 = 0.f, a3 = 0.f;
#pragma unroll 8
    for (int k = 0; k < HIDN; ++k) {
        h4 v = sp[k];
        float w = wls[hd * HIDN + k];
        a0 = fmaf((float)v.x, w, a0);
        a1 = fmaf((float)v.y, w, a1);
        a2 = fmaf((float)v.z, w, a2);
        a3 = fmaf((float)v.w, w, a3);
    }
    const size_t t = (size_t)t4 * 4;
    out[(t + 0) * 512 + tid] = a0 + bl;
    out[(t + 1) * 512 + tid] = a1 + bl;
    out[(t + 2) * 512 + tid] = a2 + bl;
    out[(t + 3) * 512 + tid] = a3 + bl;
}

extern "C" void kernel_launch(void* const* d_in, const int* in_sizes, int n_in,
                              void* d_out, int out_size, void* d_ws, size_t ws_size,
                              hipStream_t stream)
{
    const float* x    = (const float*)d_in[0];
    const float* Wih  = (const float*)d_in[1];
    const float* Whh  = (const float*)d_in[2];
    const float* bih  = (const float*)d_in[3];
    const float* bhh  = (const float*)d_in[4];
    const float* Wlin = (const float*)d_in[5];
    const float* blin = (const float*)d_in[6];

    float* out  = (float*)d_out;
    float* lstm = out + (size_t)TT * BB * HH;

    const size_t xbytes = (size_t)TT * BB * II * 2 + 4096;   // 4 MB + slack
    const size_t slab16 = (size_t)TT * BB * HH * HIDN * 2;   // 134 MB

    const bool xf16 = ws_size >= xbytes;
    _Float16* xh = (_Float16*)d_ws;
    char* slabp  = (char*)d_ws + (xf16 ? xbytes : 0);
    size_t avail = ws_size - (xf16 ? xbytes : 0);
    const int mode = (avail >= slab16) ? 1 : 2;

    if (xf16) {
        int n4 = TT * BB * II / 4;
        cvt_x_kernel<<<(n4 + 255) / 256, 256, 0, stream>>>(x, xh, n4);
    }

    _Float16* sh = (_Float16*)slabp;

    if (mode == 1 && xf16) {
        // MFMA-batched path: 32 blocks x 256 threads (head x 16-batch group)
        lstm_mfma<<<dim3(HH * 4), dim3(256), 0, stream>>>(xh, Wih, Whh, bih, bhh, sh);
        pass_lstm<<<dim3(BB * 32), dim3(256), 0, stream>>>(sh, lstm);
        pass_out <<<dim3(T4), dim3(512), 0, stream>>>(sh, Wlin, blin, out);
    } else if (mode == 1) {
        dim3 grid(BB * HH), block(64);
        lstm_wave<1, false><<<grid, block, 0, stream>>>(x, xh, Wih, Whh, bih, bhh,
                                                        Wlin, blin, out, lstm, sh);
        pass_lstm<<<dim3(BB * 32), dim3(256), 0, stream>>>(sh, lstm);
        pass_out <<<dim3(T4), dim3(512), 0, stream>>>(sh, Wlin, blin, out);
    } else {
        hipMemsetAsync(lstm, 0, (size_t)TT * BB * HIDN * 4, stream);
        dim3 grid(BB * HH), block(64);
        if (xf16)
            lstm_wave<2, true><<<grid, block, 0, stream>>>(x, xh, Wih, Whh, bih, bhh,
                                                           Wlin, blin, out, lstm, sh);
        else
            lstm_wave<2, false><<<grid, block, 0, stream>>>(x, xh, Wih, Whh, bih, bhh,
                                                            Wlin, blin, out, lstm, sh);
    }
}